// Round 4
// baseline (441.229 us; speedup 1.0000x reference)
//
#include <hip/hip_runtime.h>
#include <hip/hip_bf16.h>
#include <stdint.h>

// Problem constants
#define H2      1024
#define SEQ     512
#define BATCH   64
#define M_TOTAL (SEQ * BATCH)   // 32768 rows, row m = s*64 + b (enc layout (S,B,H2))

typedef __attribute__((ext_vector_type(8))) short short8;  // 8 bf16 (4 VGPRs)
typedef __attribute__((ext_vector_type(4))) float f32x4;   // mfma acc

__device__ __forceinline__ unsigned pack2_bf16(float lo, float hi) {
    union { __hip_bfloat162 h; unsigned u; } v;
    v.h = __float22bfloat162_rn(make_float2(lo, hi));
    return v.u;
}

__device__ __forceinline__ float fast_tanh(float x) {
    float e = __expf(2.0f * x);
    return __fdividef(e - 1.0f, e + 1.0f);
}

// Async global->LDS, 16B per lane; LDS dest = wave-uniform base + lane*16B.
__device__ __forceinline__ void gl_lds16(const unsigned short* g, unsigned short* l) {
    __builtin_amdgcn_global_load_lds(
        (const __attribute__((address_space(1))) unsigned int*)g,
        (__attribute__((address_space(3))) unsigned int*)l, 16, 0, 0);
}

// ------------------------------------------------------------------
// k_setup: fused prep. Block ranges:
//   [0,1024)     : W1 enc-slice -> bf16 K-major W1e; blocks<128 also zero logits
//   [1024,1088)  : state projection sp[b][h] = sum_k st*W1 + b1 (both layers)
//   [1088,17472) : enc fp32 -> bf16 (encb), 8 elems/thread   (full path only)
__global__ __launch_bounds__(256) void k_setup(const float* __restrict__ W1,
                                               const float* __restrict__ b1,
                                               const float* __restrict__ state,
                                               const float* __restrict__ enc,
                                               unsigned short* __restrict__ W1e,
                                               unsigned short* __restrict__ encb,
                                               float* __restrict__ logits,
                                               float* __restrict__ sp) {
    int blk = blockIdx.x, tid = threadIdx.x;
    if (blk < 1024) {
        // ---- W1e prep ----
        int i = blk * 256 + tid;
        int e = i << 2;
        int h = e >> 10, k = e & 1023;
        float4 v = *(const float4*)(W1 + (size_t)h * 3072 + 2048 + k);
        uint2 o;
        o.x = pack2_bf16(v.x, v.y);
        o.y = pack2_bf16(v.z, v.w);
        *(uint2*)(W1e + ((size_t)h << 10) + k) = o;
        if (blk < 128) logits[i] = 0.f;     // 32768 logits
    } else if (blk < 1088) {
        // ---- state projection: mT = blk-1024 (16 h-rows), all 64 b, K=2048 ----
        int mT   = blk - 1024;
        int lane = tid & 63;
        int wave = tid >> 6;                // b-tile 0..3
        int c    = lane & 15;
        int kq   = (lane >> 4) << 3;
        int h    = mT * 16 + c;
        int b    = wave * 16 + c;
        const float* ap = W1 + (size_t)h * 3072 + kq;   // state cols [0,2048)
        f32x4 acc = {0.f, 0.f, 0.f, 0.f};
        #pragma unroll 4
        for (int k0 = 0; k0 < 2048; k0 += 32) {
            int k = k0 + kq;
            float4 a0 = *(const float4*)(ap + k0);
            float4 a1 = *(const float4*)(ap + k0 + 4);
            int l = k >> 10, j = k & 1023;
            const float* bp = state + (((size_t)l * 64 + b) << 10) + j;
            float4 b0 = *(const float4*)bp;
            float4 b1v = *(const float4*)(bp + 4);
            union { short8 s; uint4 u; } fa, fb;
            fa.u.x = pack2_bf16(a0.x, a0.y); fa.u.y = pack2_bf16(a0.z, a0.w);
            fa.u.z = pack2_bf16(a1.x, a1.y); fa.u.w = pack2_bf16(a1.z, a1.w);
            fb.u.x = pack2_bf16(b0.x, b0.y); fb.u.y = pack2_bf16(b0.z, b0.w);
            fb.u.z = pack2_bf16(b1v.x, b1v.y); fb.u.w = pack2_bf16(b1v.z, b1v.w);
            acc = __builtin_amdgcn_mfma_f32_16x16x32_bf16(fa.s, fb.s, acc, 0, 0, 0);
        }
        int quad = lane >> 4;
        int bcol = wave * 16 + c;
        #pragma unroll
        for (int i = 0; i < 4; ++i) {
            int hh = mT * 16 + quad * 4 + i;
            sp[((size_t)bcol << 10) + hh] = acc[i] + b1[hh];
        }
    } else {
        // ---- enc -> bf16 ----
        size_t i = ((size_t)(blk - 1088) * 256 + tid) << 3;
        float4 v0 = *(const float4*)(enc + i);
        float4 v1 = *(const float4*)(enc + i + 4);
        uint4 o;
        o.x = pack2_bf16(v0.x, v0.y); o.y = pack2_bf16(v0.z, v0.w);
        o.z = pack2_bf16(v1.x, v1.y); o.w = pack2_bf16(v1.z, v1.w);
        *(uint4*)(encb + i) = o;
    }
}

// ------------------------------------------------------------------
// k_energy: C(32768,1024) = encb @ W1e^T, fused tanh/W2/reduce epilogue.
// R2 structure (BK=32, 16KB LDS, 4 glds/wave, wave-uniform LDS bases) with the
// MFMA-native lane permutation: region rg (1KB) holds rows [rg*16,rg*16+16) of
// the tile; lane L's 16B = (row = rg*16 + (L&15), k = (L>>4)*8). Fragment reads
// are then base + lane*16B -> stride-1 across lanes, zero bank conflicts.
#define BM 128
#define BN 128
#define BK 32

__global__ __launch_bounds__(256, 2) void k_energy(const unsigned short* __restrict__ encb,
                                                   const unsigned short* __restrict__ W1e,
                                                   const float* __restrict__ sp,
                                                   const float* __restrict__ W2,
                                                   float* __restrict__ logits) {
    __shared__ unsigned short As[BM * BK];   // 8 KB, regions of 512 shorts
    __shared__ unsigned short Bs[BN * BK];   // 8 KB
    int bid = blockIdx.x;
    int c8  = bid & 7;                // XCD id (round-robin dispatch)
    int jj  = bid >> 3;
    int mT  = c8 * 32 + (jj >> 3);    // same-mT blocks share c8 -> same XCD L2
    int nT  = jj & 7;
    int m0  = mT * BM, n0 = nT * BN;
    int tid  = threadIdx.x;
    int lane = tid & 63, wave = tid >> 6;
    int wm   = (wave >> 1) << 6;
    int wn   = (wave & 1) << 6;

    // staging: wave stages A regions {2w,2w+1} and B regions {2w,2w+1}
    int rowl = lane & 15;
    int q    = lane >> 4;
    int rg0  = wave * 2, rg1 = wave * 2 + 1;
    const unsigned short* gA0 = encb + (size_t)(m0 + rg0 * 16 + rowl) * H2 + q * 8;
    const unsigned short* gA1 = encb + (size_t)(m0 + rg1 * 16 + rowl) * H2 + q * 8;
    const unsigned short* gB0 = W1e  + (size_t)(n0 + rg0 * 16 + rowl) * H2 + q * 8;
    const unsigned short* gB1 = W1e  + (size_t)(n0 + rg1 * 16 + rowl) * H2 + q * 8;
    unsigned short* lA0 = As + rg0 * 512;    // wave-uniform LDS bases
    unsigned short* lA1 = As + rg1 * 512;
    unsigned short* lB0 = Bs + rg0 * 512;
    unsigned short* lB1 = Bs + rg1 * 512;

    f32x4 acc[4][4];
    #pragma unroll
    for (int mi = 0; mi < 4; ++mi)
        #pragma unroll
        for (int ni = 0; ni < 4; ++ni)
            acc[mi][ni] = (f32x4){0.f, 0.f, 0.f, 0.f};

    int ablk = wm >> 4;               // first A region this wave consumes
    int bblk = wn >> 4;
    const unsigned short* afb = As + ablk * 512 + lane * 8;
    const unsigned short* bfb = Bs + bblk * 512 + lane * 8;

    for (int k0 = 0; k0 < H2; k0 += BK) {
        __syncthreads();                       // prev iter's LDS reads retired
        gl_lds16(gA0 + k0, lA0);
        gl_lds16(gA1 + k0, lA1);
        gl_lds16(gB0 + k0, lB0);
        gl_lds16(gB1 + k0, lB1);
        __syncthreads();                       // vmcnt drain -> tiles visible
        short8 af[4], bf[4];
        #pragma unroll
        for (int i = 0; i < 4; ++i) {
            af[i] = *(const short8*)(afb + i * 512);
            bf[i] = *(const short8*)(bfb + i * 512);
        }
        #pragma unroll
        for (int mi = 0; mi < 4; ++mi)
            #pragma unroll
            for (int ni = 0; ni < 4; ++ni)
                acc[mi][ni] = __builtin_amdgcn_mfma_f32_16x16x32_bf16(af[mi], bf[ni], acc[mi][ni], 0, 0, 0);
    }

    // Epilogue: tanh + W2 dot, quad-shuffle reduce, atomic into logits[b][s]
    int c    = lane & 15;
    int quad = lane >> 4;
    float w2v[4];
    int   hcol[4];
    #pragma unroll
    for (int ni = 0; ni < 4; ++ni) {
        hcol[ni] = n0 + wn + ni * 16 + c;
        w2v[ni]  = W2[hcol[ni]];
    }
    #pragma unroll
    for (int mi = 0; mi < 4; ++mi) {
        #pragma unroll
        for (int i = 0; i < 4; ++i) {
            int m = m0 + wm + mi * 16 + quad * 4 + i;
            int b = m & 63;
            const float* sprow = sp + ((size_t)b << 10);
            float t = 0.f;
            #pragma unroll
            for (int ni = 0; ni < 4; ++ni) {
                float e = acc[mi][ni][i] + sprow[hcol[ni]];
                t = fmaf(fast_tanh(e), w2v[ni], t);
            }
            t += __shfl_xor(t, 1);
            t += __shfl_xor(t, 2);
            t += __shfl_xor(t, 4);
            t += __shfl_xor(t, 8);
            if (c == 0) atomicAdd(logits + (size_t)b * 512 + (m >> 6), t);
        }
    }
}

// Fallback (small ws): fp32 in-loop conversion with padded-LDS staging.
#define LDT 40
__global__ __launch_bounds__(256, 2) void k_energy_f32(const float* __restrict__ enc,
                                                       const unsigned short* __restrict__ W1e,
                                                       const float* __restrict__ sp,
                                                       const float* __restrict__ W2,
                                                       float* __restrict__ logits) {
    __shared__ unsigned short As[BM * LDT];
    __shared__ unsigned short Bs[BN * LDT];
    int bid = blockIdx.x;
    int c8  = bid & 7;
    int jj  = bid >> 3;
    int mT  = c8 * 32 + (jj >> 3);
    int nT  = jj & 7;
    int tid  = threadIdx.x;
    int lane = tid & 63, wave = tid >> 6;
    int wm   = (wave >> 1) << 6;
    int wn   = (wave & 1) << 6;
    int m0   = mT * BM, n0 = nT * BN;

    int arow = tid >> 1;
    int aseg = (tid & 1) << 4;
    const float*          apg = enc + ((size_t)(m0 + arow) << 10) + aseg;
    const unsigned short* wpg = W1e + ((size_t)(n0 + arow) << 10) + aseg;
    unsigned short* asd = As + arow * LDT + aseg;
    unsigned short* bsd = Bs + arow * LDT + aseg;

    f32x4 acc[4][4];
    #pragma unroll
    for (int mi = 0; mi < 4; ++mi)
        #pragma unroll
        for (int ni = 0; ni < 4; ++ni)
            acc[mi][ni] = (f32x4){0.f, 0.f, 0.f, 0.f};

    int c  = lane & 15;
    int kq = (lane >> 4) << 3;
    const unsigned short* afp = As + (wm + c) * LDT + kq;
    const unsigned short* bfp = Bs + (wn + c) * LDT + kq;

    for (int k0 = 0; k0 < 1024; k0 += 32) {
        float4 a0 = *(const float4*)(apg + k0);
        float4 a1 = *(const float4*)(apg + k0 + 4);
        float4 a2 = *(const float4*)(apg + k0 + 8);
        float4 a3 = *(const float4*)(apg + k0 + 12);
        uint4  w0 = *(const uint4*)(wpg + k0);
        uint4  w1 = *(const uint4*)(wpg + k0 + 8);
        uint4 pa0, pa1;
        pa0.x = pack2_bf16(a0.x, a0.y); pa0.y = pack2_bf16(a0.z, a0.w);
        pa0.z = pack2_bf16(a1.x, a1.y); pa0.w = pack2_bf16(a1.z, a1.w);
        pa1.x = pack2_bf16(a2.x, a2.y); pa1.y = pack2_bf16(a2.z, a2.w);
        pa1.z = pack2_bf16(a3.x, a3.y); pa1.w = pack2_bf16(a3.z, a3.w);
        __syncthreads();
        *(uint4*)asd       = pa0;
        *(uint4*)(asd + 8) = pa1;
        *(uint4*)bsd       = w0;
        *(uint4*)(bsd + 8) = w1;
        __syncthreads();
        short8 af[4], bf[4];
        #pragma unroll
        for (int i = 0; i < 4; ++i) {
            af[i] = *(const short8*)(afp + (i << 4) * LDT);
            bf[i] = *(const short8*)(bfp + (i << 4) * LDT);
        }
        #pragma unroll
        for (int mi = 0; mi < 4; ++mi)
            #pragma unroll
            for (int ni = 0; ni < 4; ++ni)
                acc[mi][ni] = __builtin_amdgcn_mfma_f32_16x16x32_bf16(af[mi], bf[ni], acc[mi][ni], 0, 0, 0);
    }

    int quad = lane >> 4;
    float w2v[4];
    int   hcol[4];
    #pragma unroll
    for (int ni = 0; ni < 4; ++ni) {
        hcol[ni] = n0 + wn + ni * 16 + c;
        w2v[ni]  = W2[hcol[ni]];
    }
    #pragma unroll
    for (int mi = 0; mi < 4; ++mi) {
        #pragma unroll
        for (int i = 0; i < 4; ++i) {
            int m = m0 + wm + mi * 16 + quad * 4 + i;
            int b = m & 63;
            const float* sprow = sp + ((size_t)b << 10);
            float t = 0.f;
            #pragma unroll
            for (int ni = 0; ni < 4; ++ni) {
                float e = acc[mi][ni][i] + sprow[hcol[ni]];
                t = fmaf(fast_tanh(e), w2v[ni], t);
            }
            t += __shfl_xor(t, 1);
            t += __shfl_xor(t, 2);
            t += __shfl_xor(t, 4);
            t += __shfl_xor(t, 8);
            if (c == 0) atomicAdd(logits + (size_t)b * 512 + (m >> 6), t);
        }
    }
}

// ------------------------------------------------------------------
// k_softmax: softmax over s per b; also zeroes ctx (runs before k_context).
__global__ __launch_bounds__(256) void k_softmax(const float* __restrict__ logits,
                                                 float* __restrict__ alpha,
                                                 float* __restrict__ ctx) {
    int b = blockIdx.x;
    int tid = threadIdx.x;
    int lane = tid & 63, wave = tid >> 6;
    #pragma unroll
    for (int j = 0; j < 4; ++j)
        ctx[((size_t)b << 10) + j * 256 + tid] = 0.f;
    float v0 = logits[(size_t)b * 512 + tid];
    float v1 = logits[(size_t)b * 512 + 256 + tid];
    float mx = fmaxf(v0, v1);
    #pragma unroll
    for (int o = 32; o; o >>= 1) mx = fmaxf(mx, __shfl_xor(mx, o));
    __shared__ float redm[4];
    if (lane == 0) redm[wave] = mx;
    __syncthreads();
    mx = fmaxf(fmaxf(redm[0], redm[1]), fmaxf(redm[2], redm[3]));
    float e0 = __expf(v0 - mx), e1 = __expf(v1 - mx);
    float s = e0 + e1;
    #pragma unroll
    for (int o = 32; o; o >>= 1) s += __shfl_xor(s, o);
    __shared__ float reds[4];
    if (lane == 0) reds[wave] = s;
    __syncthreads();
    s = reds[0] + reds[1] + reds[2] + reds[3];
    float inv = 1.0f / s;
    alpha[(size_t)b * 512 + tid]       = e0 * inv;
    alpha[(size_t)b * 512 + 256 + tid] = e1 * inv;
}

// ------------------------------------------------------------------
// k_context: context[b][h] = sum_s alpha[b][s] * enc[s][b][h], fp32.
__global__ __launch_bounds__(256) void k_context(const float* __restrict__ enc,
                                                 const float* __restrict__ alpha,
                                                 float* __restrict__ ctx) {
    int b  = blockIdx.x & 63;
    int sc = blockIdx.x >> 6;
    int h  = threadIdx.x << 2;
    float4 acc = make_float4(0.f, 0.f, 0.f, 0.f);
    int sbase = sc * 64;
    #pragma unroll 4
    for (int si = 0; si < 64; ++si) {
        int s = sbase + si;
        float a = alpha[(size_t)b * 512 + s];
        float4 e = *(const float4*)(enc + (((size_t)s * 64 + b) << 10) + h);
        acc.x = fmaf(a, e.x, acc.x);
        acc.y = fmaf(a, e.y, acc.y);
        acc.z = fmaf(a, e.z, acc.z);
        acc.w = fmaf(a, e.w, acc.w);
    }
    float* dst = ctx + ((size_t)b << 10) + h;
    atomicAdd(dst + 0, acc.x);
    atomicAdd(dst + 1, acc.y);
    atomicAdd(dst + 2, acc.z);
    atomicAdd(dst + 3, acc.w);
}

// ------------------------------------------------------------------
extern "C" void kernel_launch(void* const* d_in, const int* in_sizes, int n_in,
                              void* d_out, int out_size, void* d_ws, size_t ws_size,
                              hipStream_t stream) {
    const float* state = (const float*)d_in[0];   // (2, 64, 1024)
    const float* enc   = (const float*)d_in[1];   // (512, 64, 1024)
    const float* W1    = (const float*)d_in[2];   // (1024, 3072)
    const float* b1    = (const float*)d_in[3];   // (1024,)
    const float* W2    = (const float*)d_in[4];   // (1, 1024)
    // d_in[5] = b2: dropped — softmax is shift-invariant.

    float* ctx   = (float*)d_out;                 // (1,64,1024) = 65536 fp32
    float* alpha = (float*)d_out + 65536;         // (64,1,512)  = 32768 fp32

    char* ws = (char*)d_ws;
    unsigned short* W1e    = (unsigned short*)(ws);             // 2 MB bf16 [h][k]
    float*          sp     = (float*)(ws + 2097152);            // 256 KB [b][h]
    float*          logits = (float*)(ws + 2097152 + 262144);   // 128 KB [b][s]
    unsigned short* encb   = (unsigned short*)(ws + 2097152 + 262144 + 131072); // 64 MB

    const size_t need_full = 2097152 + 262144 + 131072 + (size_t)M_TOTAL * H2 * 2;
    bool full = ws_size >= need_full;

    k_setup<<<full ? 17472 : 1088, 256, 0, stream>>>(W1, b1, state, enc, W1e, encb, logits, sp);
    if (full) {
        k_energy<<<M_TOTAL / BM * (H2 / BN), 256, 0, stream>>>(encb, W1e, sp, W2, logits);
    } else {
        k_energy_f32<<<M_TOTAL / BM * (H2 / BN), 256, 0, stream>>>(enc, W1e, sp, W2, logits);
    }
    k_softmax<<<64, 256, 0, stream>>>(logits, alpha, ctx);
    k_context<<<512, 256, 0, stream>>>(enc, alpha, ctx);
}

// Round 5
// 385.452 us; speedup vs baseline: 1.1447x; 1.1447x over previous
//
#include <hip/hip_runtime.h>
#include <hip/hip_bf16.h>
#include <stdint.h>

// Problem constants
#define H2      1024
#define SEQ     512
#define BATCH   64
#define M_TOTAL (SEQ * BATCH)   // 32768 rows, row m = s*64 + b (enc layout (S,B,H2))

typedef __attribute__((ext_vector_type(8))) short short8;  // 8 bf16 (4 VGPRs)
typedef __attribute__((ext_vector_type(4))) float f32x4;   // mfma acc

__device__ __forceinline__ unsigned pack2_bf16(float lo, float hi) {
    union { __hip_bfloat162 h; unsigned u; } v;
    v.h = __float22bfloat162_rn(make_float2(lo, hi));
    return v.u;
}

__device__ __forceinline__ float fast_tanh(float x) {
    float e = __expf(2.0f * x);
    return __fdividef(e - 1.0f, e + 1.0f);
}

// Async global->LDS, 16B per lane; LDS dest = wave-uniform base + lane*16B.
__device__ __forceinline__ void gl_lds16(const unsigned short* g, unsigned short* l) {
    __builtin_amdgcn_global_load_lds(
        (const __attribute__((address_space(1))) unsigned int*)g,
        (__attribute__((address_space(3))) unsigned int*)l, 16, 0, 0);
}

// Swizzled operand layout (MFMA-fragment-major):
//   region gr = RB*32 + KC  (RB = row>>4, KC = k>>5), 512 shorts each.
//   chunk L in [0,64): 8 shorts = (row = RB*16 + (L&15), k = KC*32 + (L>>4)*8).
// k_energy glds then reads base + lane*16B: 1KB fully contiguous per instr,
// and the LDS image is exactly MFMA fragment order (zero bank conflicts).

// ------------------------------------------------------------------
// k_setup: fused prep. Block ranges:
//   [0,512)      : W1 enc-slice -> bf16 W1e (swizzled if swz, else plain [h][k])
//   [512,640)    : zero logits (32768)
//   [640,704)    : state projection sp[b][h] = sum_k st*W1 + b1 (both layers)
//   [704,17088)  : enc fp32 -> bf16 swizzled encb   (full path only)
__global__ __launch_bounds__(256) void k_setup(const float* __restrict__ W1,
                                               const float* __restrict__ b1,
                                               const float* __restrict__ state,
                                               const float* __restrict__ enc,
                                               unsigned short* __restrict__ W1e,
                                               unsigned short* __restrict__ encb,
                                               float* __restrict__ logits,
                                               float* __restrict__ sp,
                                               int swz) {
    int blk = blockIdx.x, tid = threadIdx.x;
    int lane = tid & 63;
    if (blk < 512) {
        // ---- W1e prep: 4 regions per block (wave w -> region blk*4+w) ----
        if (swz) {
            int gr = blk * 4 + (tid >> 6);
            int L  = ((lane & 3) << 4) | (lane >> 2);   // read-coalescing perm
            int h  = ((gr >> 5) << 4) + (L & 15);
            int k  = ((gr & 31) << 5) + ((L >> 4) << 3);
            const float* src = W1 + (size_t)h * 3072 + 2048 + k;
            float4 v0 = *(const float4*)(src);
            float4 v1 = *(const float4*)(src + 4);
            uint4 o;
            o.x = pack2_bf16(v0.x, v0.y); o.y = pack2_bf16(v0.z, v0.w);
            o.z = pack2_bf16(v1.x, v1.y); o.w = pack2_bf16(v1.z, v1.w);
            *(uint4*)(W1e + (size_t)gr * 512 + L * 8) = o;
        } else {
            // plain [h][k] layout for the fallback GEMM; 8 elems/thread
            int i = blk * 256 + tid;
            int e = i << 3;
            int h = e >> 10, k = e & 1023;
            const float* src = W1 + (size_t)h * 3072 + 2048 + k;
            float4 v0 = *(const float4*)(src);
            float4 v1 = *(const float4*)(src + 4);
            uint4 o;
            o.x = pack2_bf16(v0.x, v0.y); o.y = pack2_bf16(v0.z, v0.w);
            o.z = pack2_bf16(v1.x, v1.y); o.w = pack2_bf16(v1.z, v1.w);
            *(uint4*)(W1e + ((size_t)h << 10) + k) = o;
        }
    } else if (blk < 640) {
        logits[(blk - 512) * 256 + tid] = 0.f;
    } else if (blk < 704) {
        // ---- state projection: mT = blk-640 (16 h-rows), all 64 b, K=2048 ----
        int mT   = blk - 640;
        int wave = tid >> 6;                // b-tile 0..3
        int c    = lane & 15;
        int kq   = (lane >> 4) << 3;
        int h    = mT * 16 + c;
        int b    = wave * 16 + c;
        const float* ap = W1 + (size_t)h * 3072 + kq;   // state cols [0,2048)
        f32x4 acc = {0.f, 0.f, 0.f, 0.f};
        #pragma unroll 4
        for (int k0 = 0; k0 < 2048; k0 += 32) {
            int k = k0 + kq;
            float4 a0 = *(const float4*)(ap + k0);
            float4 a1 = *(const float4*)(ap + k0 + 4);
            int l = k >> 10, j = k & 1023;
            const float* bp = state + (((size_t)l * 64 + b) << 10) + j;
            float4 b0 = *(const float4*)bp;
            float4 b1v = *(const float4*)(bp + 4);
            union { short8 s; uint4 u; } fa, fb;
            fa.u.x = pack2_bf16(a0.x, a0.y); fa.u.y = pack2_bf16(a0.z, a0.w);
            fa.u.z = pack2_bf16(a1.x, a1.y); fa.u.w = pack2_bf16(a1.z, a1.w);
            fb.u.x = pack2_bf16(b0.x, b0.y); fb.u.y = pack2_bf16(b0.z, b0.w);
            fb.u.z = pack2_bf16(b1v.x, b1v.y); fb.u.w = pack2_bf16(b1v.z, b1v.w);
            acc = __builtin_amdgcn_mfma_f32_16x16x32_bf16(fa.s, fb.s, acc, 0, 0, 0);
        }
        int quad = lane >> 4;
        int bcol = wave * 16 + c;
        #pragma unroll
        for (int i = 0; i < 4; ++i) {
            int hh = mT * 16 + quad * 4 + i;
            sp[((size_t)bcol << 10) + hh] = acc[i] + b1[hh];
        }
    } else {
        // ---- enc -> swizzled bf16: 4 regions per block ----
        int gr = (blk - 704) * 4 + (tid >> 6);          // [0, 65536)
        int L  = ((lane & 3) << 4) | (lane >> 2);
        int m  = ((gr >> 5) << 4) + (L & 15);
        int k  = ((gr & 31) << 5) + ((L >> 4) << 3);
        const float* src = enc + (size_t)m * 1024 + k;
        float4 v0 = *(const float4*)(src);
        float4 v1 = *(const float4*)(src + 4);
        uint4 o;
        o.x = pack2_bf16(v0.x, v0.y); o.y = pack2_bf16(v0.z, v0.w);
        o.z = pack2_bf16(v1.x, v1.y); o.w = pack2_bf16(v1.z, v1.w);
        *(uint4*)(encb + (size_t)gr * 512 + L * 8) = o;
    }
}

// ------------------------------------------------------------------
// k_energy: C(32768,1024) = encb @ W1e^T, fused tanh/W2/reduce epilogue.
// Operands are pre-swizzled in global memory: glds reads are 1KB contiguous
// (base + lane*16B), LDS image is MFMA fragment order (zero conflicts).
#define BM 128
#define BN 128
#define BK 32

__global__ __launch_bounds__(256, 2) void k_energy(const unsigned short* __restrict__ encb,
                                                   const unsigned short* __restrict__ W1e,
                                                   const float* __restrict__ sp,
                                                   const float* __restrict__ W2,
                                                   float* __restrict__ logits) {
    __shared__ unsigned short As[BM * BK];   // 8 KB, regions of 512 shorts
    __shared__ unsigned short Bs[BN * BK];   // 8 KB
    int bid = blockIdx.x;
    int c8  = bid & 7;                // XCD id (round-robin dispatch)
    int jj  = bid >> 3;
    int mT  = c8 * 32 + (jj >> 3);    // same-mT blocks share c8 -> same XCD L2
    int nT  = jj & 7;
    int n0  = nT * BN;
    int m0  = mT * BM;
    int tid  = threadIdx.x;
    int lane = tid & 63, wave = tid >> 6;
    int wm   = (wave >> 1) << 6;
    int wn   = (wave & 1) << 6;

    // staging: wave stages A regions {2w,2w+1} and B regions {2w,2w+1}.
    // Global: swizzled layout, region (RB, KC) at (RB*32+KC)*512 shorts;
    // per-iter advance = KC+1 -> +512 shorts = k0*16.
    int rg0 = wave * 2, rg1 = wave * 2 + 1;
    const unsigned short* gA0 = encb + ((size_t)(mT * 8 + rg0) * 32) * 512 + lane * 8;
    const unsigned short* gA1 = encb + ((size_t)(mT * 8 + rg1) * 32) * 512 + lane * 8;
    const unsigned short* gB0 = W1e  + ((size_t)(nT * 8 + rg0) * 32) * 512 + lane * 8;
    const unsigned short* gB1 = W1e  + ((size_t)(nT * 8 + rg1) * 32) * 512 + lane * 8;
    unsigned short* lA0 = As + rg0 * 512;    // wave-uniform LDS bases
    unsigned short* lA1 = As + rg1 * 512;
    unsigned short* lB0 = Bs + rg0 * 512;
    unsigned short* lB1 = Bs + rg1 * 512;

    f32x4 acc[4][4];
    #pragma unroll
    for (int mi = 0; mi < 4; ++mi)
        #pragma unroll
        for (int ni = 0; ni < 4; ++ni)
            acc[mi][ni] = (f32x4){0.f, 0.f, 0.f, 0.f};

    int ablk = wm >> 4;               // first A region this wave consumes
    int bblk = wn >> 4;
    const unsigned short* afb = As + ablk * 512 + lane * 8;
    const unsigned short* bfb = Bs + bblk * 512 + lane * 8;

    for (int k0 = 0; k0 < H2; k0 += BK) {
        int go = k0 * 16;                      // swizzled-layout offset (shorts)
        __syncthreads();                       // prev iter's LDS reads retired
        gl_lds16(gA0 + go, lA0);
        gl_lds16(gA1 + go, lA1);
        gl_lds16(gB0 + go, lB0);
        gl_lds16(gB1 + go, lB1);
        __syncthreads();                       // vmcnt drain -> tiles visible
        short8 af[4], bf[4];
        #pragma unroll
        for (int i = 0; i < 4; ++i) {
            af[i] = *(const short8*)(afb + i * 512);
            bf[i] = *(const short8*)(bfb + i * 512);
        }
        #pragma unroll
        for (int mi = 0; mi < 4; ++mi)
            #pragma unroll
            for (int ni = 0; ni < 4; ++ni)
                acc[mi][ni] = __builtin_amdgcn_mfma_f32_16x16x32_bf16(af[mi], bf[ni], acc[mi][ni], 0, 0, 0);
    }

    // Epilogue: tanh + W2 dot, quad-shuffle reduce, atomic into logits[b][s]
    int c    = lane & 15;
    int quad = lane >> 4;
    float w2v[4];
    int   hcol[4];
    #pragma unroll
    for (int ni = 0; ni < 4; ++ni) {
        hcol[ni] = n0 + wn + ni * 16 + c;
        w2v[ni]  = W2[hcol[ni]];
    }
    #pragma unroll
    for (int mi = 0; mi < 4; ++mi) {
        #pragma unroll
        for (int i = 0; i < 4; ++i) {
            int m = m0 + wm + mi * 16 + quad * 4 + i;
            int b = m & 63;
            const float* sprow = sp + ((size_t)b << 10);
            float t = 0.f;
            #pragma unroll
            for (int ni = 0; ni < 4; ++ni) {
                float e = acc[mi][ni][i] + sprow[hcol[ni]];
                t = fmaf(fast_tanh(e), w2v[ni], t);
            }
            t += __shfl_xor(t, 1);
            t += __shfl_xor(t, 2);
            t += __shfl_xor(t, 4);
            t += __shfl_xor(t, 8);
            if (c == 0) atomicAdd(logits + (size_t)b * 512 + (m >> 6), t);
        }
    }
}

// Fallback (small ws): fp32 in-loop conversion, plain W1e [h][k] layout.
#define LDT 40
__global__ __launch_bounds__(256, 2) void k_energy_f32(const float* __restrict__ enc,
                                                       const unsigned short* __restrict__ W1e,
                                                       const float* __restrict__ sp,
                                                       const float* __restrict__ W2,
                                                       float* __restrict__ logits) {
    __shared__ unsigned short As[BM * LDT];
    __shared__ unsigned short Bs[BN * LDT];
    int bid = blockIdx.x;
    int c8  = bid & 7;
    int jj  = bid >> 3;
    int mT  = c8 * 32 + (jj >> 3);
    int nT  = jj & 7;
    int tid  = threadIdx.x;
    int lane = tid & 63, wave = tid >> 6;
    int wm   = (wave >> 1) << 6;
    int wn   = (wave & 1) << 6;
    int m0   = mT * BM, n0 = nT * BN;

    int arow = tid >> 1;
    int aseg = (tid & 1) << 4;
    const float*          apg = enc + ((size_t)(m0 + arow) << 10) + aseg;
    const unsigned short* wpg = W1e + ((size_t)(n0 + arow) << 10) + aseg;
    unsigned short* asd = As + arow * LDT + aseg;
    unsigned short* bsd = Bs + arow * LDT + aseg;

    f32x4 acc[4][4];
    #pragma unroll
    for (int mi = 0; mi < 4; ++mi)
        #pragma unroll
        for (int ni = 0; ni < 4; ++ni)
            acc[mi][ni] = (f32x4){0.f, 0.f, 0.f, 0.f};

    int c  = lane & 15;
    int kq = (lane >> 4) << 3;
    const unsigned short* afp = As + (wm + c) * LDT + kq;
    const unsigned short* bfp = Bs + (wn + c) * LDT + kq;

    for (int k0 = 0; k0 < 1024; k0 += 32) {
        float4 a0 = *(const float4*)(apg + k0);
        float4 a1 = *(const float4*)(apg + k0 + 4);
        float4 a2 = *(const float4*)(apg + k0 + 8);
        float4 a3 = *(const float4*)(apg + k0 + 12);
        uint4  w0 = *(const uint4*)(wpg + k0);
        uint4  w1 = *(const uint4*)(wpg + k0 + 8);
        uint4 pa0, pa1;
        pa0.x = pack2_bf16(a0.x, a0.y); pa0.y = pack2_bf16(a0.z, a0.w);
        pa0.z = pack2_bf16(a1.x, a1.y); pa0.w = pack2_bf16(a1.z, a1.w);
        pa1.x = pack2_bf16(a2.x, a2.y); pa1.y = pack2_bf16(a2.z, a2.w);
        pa1.z = pack2_bf16(a3.x, a3.y); pa1.w = pack2_bf16(a3.z, a3.w);
        __syncthreads();
        *(uint4*)asd       = pa0;
        *(uint4*)(asd + 8) = pa1;
        *(uint4*)bsd       = w0;
        *(uint4*)(bsd + 8) = w1;
        __syncthreads();
        short8 af[4], bf[4];
        #pragma unroll
        for (int i = 0; i < 4; ++i) {
            af[i] = *(const short8*)(afp + (i << 4) * LDT);
            bf[i] = *(const short8*)(bfp + (i << 4) * LDT);
        }
        #pragma unroll
        for (int mi = 0; mi < 4; ++mi)
            #pragma unroll
            for (int ni = 0; ni < 4; ++ni)
                acc[mi][ni] = __builtin_amdgcn_mfma_f32_16x16x32_bf16(af[mi], bf[ni], acc[mi][ni], 0, 0, 0);
    }

    int quad = lane >> 4;
    float w2v[4];
    int   hcol[4];
    #pragma unroll
    for (int ni = 0; ni < 4; ++ni) {
        hcol[ni] = n0 + wn + ni * 16 + c;
        w2v[ni]  = W2[hcol[ni]];
    }
    #pragma unroll
    for (int mi = 0; mi < 4; ++mi) {
        #pragma unroll
        for (int i = 0; i < 4; ++i) {
            int m = m0 + wm + mi * 16 + quad * 4 + i;
            int b = m & 63;
            const float* sprow = sp + ((size_t)b << 10);
            float t = 0.f;
            #pragma unroll
            for (int ni = 0; ni < 4; ++ni) {
                float e = acc[mi][ni][i] + sprow[hcol[ni]];
                t = fmaf(fast_tanh(e), w2v[ni], t);
            }
            t += __shfl_xor(t, 1);
            t += __shfl_xor(t, 2);
            t += __shfl_xor(t, 4);
            t += __shfl_xor(t, 8);
            if (c == 0) atomicAdd(logits + (size_t)b * 512 + (m >> 6), t);
        }
    }
}

// ------------------------------------------------------------------
// k_softmax: softmax over s per b; also zeroes ctx (runs before k_context).
__global__ __launch_bounds__(256) void k_softmax(const float* __restrict__ logits,
                                                 float* __restrict__ alpha,
                                                 float* __restrict__ ctx) {
    int b = blockIdx.x;
    int tid = threadIdx.x;
    int lane = tid & 63, wave = tid >> 6;
    #pragma unroll
    for (int j = 0; j < 4; ++j)
        ctx[((size_t)b << 10) + j * 256 + tid] = 0.f;
    float v0 = logits[(size_t)b * 512 + tid];
    float v1 = logits[(size_t)b * 512 + 256 + tid];
    float mx = fmaxf(v0, v1);
    #pragma unroll
    for (int o = 32; o; o >>= 1) mx = fmaxf(mx, __shfl_xor(mx, o));
    __shared__ float redm[4];
    if (lane == 0) redm[wave] = mx;
    __syncthreads();
    mx = fmaxf(fmaxf(redm[0], redm[1]), fmaxf(redm[2], redm[3]));
    float e0 = __expf(v0 - mx), e1 = __expf(v1 - mx);
    float s = e0 + e1;
    #pragma unroll
    for (int o = 32; o; o >>= 1) s += __shfl_xor(s, o);
    __shared__ float reds[4];
    if (lane == 0) reds[wave] = s;
    __syncthreads();
    s = reds[0] + reds[1] + reds[2] + reds[3];
    float inv = 1.0f / s;
    alpha[(size_t)b * 512 + tid]       = e0 * inv;
    alpha[(size_t)b * 512 + 256 + tid] = e1 * inv;
}

// ------------------------------------------------------------------
// k_context: context[b][h] = sum_s alpha[b][s] * enc[s][b][h], fp32.
__global__ __launch_bounds__(256) void k_context(const float* __restrict__ enc,
                                                 const float* __restrict__ alpha,
                                                 float* __restrict__ ctx) {
    int b  = blockIdx.x & 63;
    int sc = blockIdx.x >> 6;
    int h  = threadIdx.x << 2;
    float4 acc = make_float4(0.f, 0.f, 0.f, 0.f);
    int sbase = sc * 64;
    #pragma unroll 4
    for (int si = 0; si < 64; ++si) {
        int s = sbase + si;
        float a = alpha[(size_t)b * 512 + s];
        float4 e = *(const float4*)(enc + (((size_t)s * 64 + b) << 10) + h);
        acc.x = fmaf(a, e.x, acc.x);
        acc.y = fmaf(a, e.y, acc.y);
        acc.z = fmaf(a, e.z, acc.z);
        acc.w = fmaf(a, e.w, acc.w);
    }
    float* dst = ctx + ((size_t)b << 10) + h;
    atomicAdd(dst + 0, acc.x);
    atomicAdd(dst + 1, acc.y);
    atomicAdd(dst + 2, acc.z);
    atomicAdd(dst + 3, acc.w);
}

// ------------------------------------------------------------------
extern "C" void kernel_launch(void* const* d_in, const int* in_sizes, int n_in,
                              void* d_out, int out_size, void* d_ws, size_t ws_size,
                              hipStream_t stream) {
    const float* state = (const float*)d_in[0];   // (2, 64, 1024)
    const float* enc   = (const float*)d_in[1];   // (512, 64, 1024)
    const float* W1    = (const float*)d_in[2];   // (1024, 3072)
    const float* b1    = (const float*)d_in[3];   // (1024,)
    const float* W2    = (const float*)d_in[4];   // (1, 1024)
    // d_in[5] = b2: dropped — softmax is shift-invariant.

    float* ctx   = (float*)d_out;                 // (1,64,1024) = 65536 fp32
    float* alpha = (float*)d_out + 65536;         // (64,1,512)  = 32768 fp32

    char* ws = (char*)d_ws;
    unsigned short* W1e    = (unsigned short*)(ws);             // 2 MB bf16
    float*          sp     = (float*)(ws + 2097152);            // 256 KB [b][h]
    float*          logits = (float*)(ws + 2097152 + 262144);   // 128 KB [b][s]
    unsigned short* encb   = (unsigned short*)(ws + 2097152 + 262144 + 131072); // 64 MB

    const size_t need_full = 2097152 + 262144 + 131072 + (size_t)M_TOTAL * H2 * 2;
    bool full = ws_size >= need_full;

    k_setup<<<full ? 17088 : 704, 256, 0, stream>>>(W1, b1, state, enc, W1e, encb,
                                                    logits, sp, full ? 1 : 0);
    if (full) {
        k_energy<<<M_TOTAL / BM * (H2 / BN), 256, 0, stream>>>(encb, W1e, sp, W2, logits);
    } else {
        k_energy_f32<<<M_TOTAL / BM * (H2 / BN), 256, 0, stream>>>(enc, W1e, sp, W2, logits);
    }
    k_softmax<<<64, 256, 0, stream>>>(logits, alpha, ctx);
    k_context<<<512, 256, 0, stream>>>(enc, alpha, ctx);
}